// Round 13
// baseline (413.048 us; speedup 1.0000x reference)
//
#include <hip/hip_runtime.h>
#include <cmath>

typedef __bf16 bf16;
typedef __attribute__((ext_vector_type(8))) __bf16 bf16x8;
typedef __attribute__((ext_vector_type(4))) __bf16 bf16x4;
typedef __attribute__((ext_vector_type(4))) float f32x4;

#define DEVINL __device__ __forceinline__

DEVINL void gload16(const void* g, void* l) {
    __builtin_amdgcn_global_load_lds((const __attribute__((address_space(1))) void*)g,
                                     (__attribute__((address_space(3))) void*)l, 16, 0, 0);
}

// ---------------- utility kernels ----------------

__global__ void cast_bf16_kernel(const float* __restrict__ in, bf16* __restrict__ out, int n4) {
    int i = blockIdx.x * 256 + threadIdx.x;
    if (i < n4) {
        float4 v = ((const float4*)in)[i];
        bf16x4 o;
        o[0] = (bf16)v.x; o[1] = (bf16)v.y; o[2] = (bf16)v.z; o[3] = (bf16)v.w;
        ((bf16x4*)out)[i] = o;
    }
}

// pb scaled by 0.125*log2e, mask scaled by log2e, both -> bf16, one launch
__global__ void prep_pm_kernel(const float* __restrict__ pb, const float* __restrict__ mask,
                               bf16* __restrict__ pbs, bf16* __restrict__ maskb,
                               int n1, int n2) {
    const int i = blockIdx.x * 256 + threadIdx.x;
    const float c1 = 0.18033688011112042f;   // 0.125 * log2(e)
    const float c2 = 1.4426950408889634f;    // log2(e)
    if (i < n1) {
        float4 v = ((const float4*)pb)[i];
        bf16x4 o;
        o[0] = (bf16)(v.x * c1); o[1] = (bf16)(v.y * c1);
        o[2] = (bf16)(v.z * c1); o[3] = (bf16)(v.w * c1);
        ((bf16x4*)pbs)[i] = o;
    } else if (i < n1 + n2) {
        const int j = i - n1;
        float4 v = ((const float4*)mask)[j];
        bf16x4 o;
        o[0] = (bf16)(v.x * c2); o[1] = (bf16)(v.y * c2);
        o[2] = (bf16)(v.z * c2); o[3] = (bf16)(v.w * c2);
        ((bf16x4*)maskb)[j] = o;
    }
}

// in: [R][C] f32  ->  out: [C][R] bf16
__global__ void tcast_kernel(const float* __restrict__ in, bf16* __restrict__ out, int R, int C) {
    __shared__ float t[32][33];
    int tx = threadIdx.x & 31, ty = threadIdx.x >> 5;
    int r0 = blockIdx.y * 32, c0 = blockIdx.x * 32;
#pragma unroll
    for (int i = 0; i < 4; ++i)
        t[ty + 8 * i][tx] = in[(size_t)(r0 + ty + 8 * i) * C + c0 + tx];
    __syncthreads();
#pragma unroll
    for (int i = 0; i < 4; ++i)
        out[(size_t)(c0 + ty + 8 * i) * R + r0 + tx] = (bf16)t[tx][ty + 8 * i];
}

__global__ void concat_bias_kernel(const float* __restrict__ a, const float* __restrict__ b,
                                   float* __restrict__ out) {
    int i = blockIdx.x * 256 + threadIdx.x;
    if (i < 1536) out[i] = (i < 768) ? a[i] : b[i - 768];
}

// ---------------- GEMM: C[M][N] = A[M][K] * Bt[N][K]^T + bias ----------------
// 128 x BN tile, 4 waves, single-buffered LDS, TLP-hidden staging (proven
// round-4 structure). MODE 0: bias[col]->bf16 row-major; MODE 2: +gelu;
// MODE 3: bias[row], store into vT layout ((col>>10)*768+row)*1024+(col&1023).
// T1 XCD swizzle (grid %8==0).
template<int MODE, int BN>
__global__ __launch_bounds__(256, 4) void gemm_kernel(const bf16* __restrict__ A, const bf16* __restrict__ Bt,
                                                      const float* __restrict__ bias,
                                                      bf16* __restrict__ Cb,
                                                      int M, int N, int K, int ldc) {
    constexpr int NI = BN / 32;
    constexpr int BLOADS = BN / 32;
    __shared__ __align__(16) bf16 As[128 * 64];
    __shared__ __align__(16) bf16 Bs[BN * 64];
    const int tid = threadIdx.x;
    const int wid = tid >> 6, lane = tid & 63;
    const int L = blockIdx.y * gridDim.x + blockIdx.x;
    const int cpx = (gridDim.x * gridDim.y) >> 3;
    const int wg = (L & 7) * cpx + (L >> 3);
    const int m0 = (wg / gridDim.x) * 128, n0 = (wg % gridDim.x) * BN;
    const int wr = (wid >> 1) * 64, wc = (wid & 1) * (BN / 2);
    const int lg = lane >> 4, l15 = lane & 15;
    f32x4 acc[4][NI] = {};

    for (int k0 = 0; k0 < K; k0 += 64) {
        __syncthreads();
#pragma unroll
        for (int i = 0; i < 4; ++i) {
            const int cbase = (wid * 4 + i) * 1024;
            const int td = cbase + lane * 16;
            const int row = td >> 7;
            const int s16 = ((td >> 4) & 7) ^ (row & 7);
            gload16(A + (size_t)(m0 + row) * K + k0 + s16 * 8, (char*)As + cbase);
        }
#pragma unroll
        for (int i = 0; i < BLOADS; ++i) {
            const int cbase = (wid * BLOADS + i) * 1024;
            const int td = cbase + lane * 16;
            const int row = td >> 7;
            const int s16 = ((td >> 4) & 7) ^ (row & 7);
            gload16(Bt + (size_t)(n0 + row) * K + k0 + s16 * 8, (char*)Bs + cbase);
        }
        __syncthreads();
#pragma unroll
        for (int kk = 0; kk < 2; ++kk) {
            bf16x8 af[4], bfr[NI];
#pragma unroll
            for (int mi = 0; mi < 4; ++mi) {
                int ra = wr + mi * 16 + l15;
                int off = (ra * 128 + (kk * 32 + 8 * lg) * 2) ^ ((ra & 7) << 4);
                af[mi] = *(const bf16x8*)((const char*)As + off);
            }
#pragma unroll
            for (int ni = 0; ni < NI; ++ni) {
                int rb = wc + ni * 16 + l15;
                int off = (rb * 128 + (kk * 32 + 8 * lg) * 2) ^ ((rb & 7) << 4);
                bfr[ni] = *(const bf16x8*)((const char*)Bs + off);
            }
#pragma unroll
            for (int mi = 0; mi < 4; ++mi)
#pragma unroll
                for (int ni = 0; ni < NI; ++ni)
                    acc[mi][ni] = __builtin_amdgcn_mfma_f32_16x16x32_bf16(af[mi], bfr[ni], acc[mi][ni], 0, 0, 0);
        }
    }
#pragma unroll
    for (int mi = 0; mi < 4; ++mi) {
#pragma unroll
        for (int r = 0; r < 4; ++r) {
            const int row = m0 + wr + mi * 16 + lg * 4 + r;
#pragma unroll
            for (int ni = 0; ni < NI; ++ni) {
                const int col = n0 + wc + ni * 16 + l15;
                float v = acc[mi][ni][r] + bias[(MODE == 3) ? row : col];
                if (MODE == 2) v = v * 0.5f * (1.0f + erff(v * 0.70710678118654752f));
                if (MODE == 3)
                    Cb[((size_t)(col >> 10) * 768 + row) * 1024 + (col & 1023)] = (bf16)v;
                else
                    Cb[(size_t)row * ldc + col] = (bf16)v;
            }
        }
    }
}

// ---------------- flash attention ----------------
// qk: [8192][1536] bf16 (Q|K per head); vT: [96][64][1024]; grid (8 qb, 96 bh).
// K LDS-staged 3-deep (prefetch depth 2), V LDS-staged 2-deep (depth 1, issued
// at tile top so it has a full tile of compute to land). LDS 40KB -> exactly
// 4 blocks/CU (vs 3 at 49KB): +33% resident waves on a latency-bound kernel.
// K LDS rows permuted by phys(i)=bits [i5][i3][i2][i4][i1][i0] so the QK^T
// per-lane k-set equals the PV B-fragment layout; P stays in registers.
// Per-tile vmem queue: pbv/mkv(8) -> stageV t+1(2) -> stageK t+2(2). Softmax's
// automatic wait on pbv leaves the 4 stage loads in flight. Barrier:
// s_waitcnt vmcnt(2) (drain V t+1, keep K t+2 flying; vmcnt(0) for t>=14
// where V15 is newest) + raw s_barrier. In-order vmem retirement makes the
// counts exact; buffer write-after-read is protected by the barrier.
__global__ __launch_bounds__(256, 4) void attn_kernel(const bf16* __restrict__ qk,
                                                      const bf16* __restrict__ pbs,
                                                      const bf16* __restrict__ maskb,
                                                      const bf16* __restrict__ vT,
                                                      bf16* __restrict__ ctx) {
    __shared__ __align__(16) bf16 Kb[3][64 * 64];
    __shared__ __align__(16) bf16 Vb[2][64 * 64];
    const int tid = threadIdx.x, wid = tid >> 6, lane = tid & 63;
    const int bh = blockIdx.y, b = bh / 12, h = bh % 12;
    const int q0 = blockIdx.x * 128 + wid * 32;
    const int lg = lane >> 4, l15 = lane & 15;
    const float cqk = 0.18033688011112042f;  // 0.125 * log2(e)

    bf16x8 aq[2][2];
#pragma unroll
    for (int qs = 0; qs < 2; ++qs) {
        const size_t r = (size_t)(b * 1024 + q0 + qs * 16 + l15) * 1536 + h * 64 + 8 * lg;
        aq[qs][0] = *(const bf16x8*)(qk + r);
        aq[qs][1] = *(const bf16x8*)(qk + r + 32);
    }

    auto stageK = [&](int tt, int pp) {
#pragma unroll
        for (int rd = 0; rd < 2; ++rd) {
            const int n = rd * 256 + tid;
            const int i = n >> 3, sl = n & 7, c = sl ^ (i & 7);
            const int sig = (i & 32) | ((i & 12) << 1) | ((i & 16) >> 2) | (i & 3);
            gload16(qk + (size_t)(b * 1024 + tt * 64 + sig) * 1536 + 768 + h * 64 + c * 8,
                    (char*)Kb[pp] + (rd * 256 + wid * 64) * 16);
        }
    };
    auto stageV = [&](int tt, int pp) {
#pragma unroll
        for (int rd = 0; rd < 2; ++rd) {
            const int n = rd * 256 + tid;
            const int i = n >> 3, sl = n & 7, c = sl ^ (i & 7);
            gload16(vT + ((size_t)bh * 64 + i) * 1024 + tt * 64 + c * 8,
                    (char*)Vb[pp] + (rd * 256 + wid * 64) * 16);
        }
    };

    float mrun[2] = {-1e30f, -1e30f}, lsum[2] = {0.f, 0.f};
    f32x4 acc[2][4] = {};

    stageK(0, 0);
    stageV(0, 0);
    stageK(1, 1);
    asm volatile("s_waitcnt vmcnt(2)" ::: "memory");
    __builtin_amdgcn_s_barrier();
    for (int t = 0; t < 16; ++t) {
        const int p = t % 3;
        const int vcur = t & 1;
        const int k0 = t * 64;
        bf16x8 pbv[2][2], mkv[2][2];
#pragma unroll
        for (int qs = 0; qs < 2; ++qs) {
            const int q = q0 + qs * 16 + l15;
            const bf16* pr = pbs + ((size_t)h * 1024 + q) * 1024 + k0 + lg * 8;
            const bf16* mr = maskb + ((size_t)b * 1024 + q) * 1024 + k0 + lg * 8;
            pbv[qs][0] = *(const bf16x8*)pr;  pbv[qs][1] = *(const bf16x8*)(pr + 32);
            mkv[qs][0] = *(const bf16x8*)mr;  mkv[qs][1] = *(const bf16x8*)(mr + 32);
        }
        if (t < 15) stageV(t + 1, vcur ^ 1);
        if (t < 14) stageK(t + 2, (t + 2) % 3);

        bf16x8 bk[4][2];
#pragma unroll
        for (int kt = 0; kt < 4; ++kt) {
            const int row = kt * 16 + l15;
            const int byte = (row * 128 + lg * 16) ^ ((row & 7) << 4);
            bk[kt][0] = *(const bf16x8*)((const char*)Kb[p] + byte);
            bk[kt][1] = *(const bf16x8*)((const char*)Kb[p] + (byte ^ 64));
        }
        f32x4 s[2][4];
        __builtin_amdgcn_s_setprio(1);
#pragma unroll
        for (int qs = 0; qs < 2; ++qs)
#pragma unroll
            for (int kt = 0; kt < 4; ++kt) {
                f32x4 z = {};
                z = __builtin_amdgcn_mfma_f32_16x16x32_bf16(bk[kt][0], aq[qs][0], z, 0, 0, 0);
                z = __builtin_amdgcn_mfma_f32_16x16x32_bf16(bk[kt][1], aq[qs][1], z, 0, 0, 0);
                s[qs][kt] = z;
            }
        __builtin_amdgcn_s_setprio(0);
#pragma unroll
        for (int qs = 0; qs < 2; ++qs)
#pragma unroll
            for (int kt = 0; kt < 4; ++kt)
#pragma unroll
                for (int r = 0; r < 4; ++r) {
                    const int j = (kt & 1) * 4 + r;
                    s[qs][kt][r] = s[qs][kt][r] * cqk
                                 + (float)pbv[qs][kt >> 1][j]
                                 + (float)mkv[qs][kt >> 1][j];
                }
        // online softmax with defer-max (T13): skip rescale while growth <= 6
        bf16x8 po[2][2];
#pragma unroll
        for (int qs = 0; qs < 2; ++qs) {
            float tm = s[qs][0][0];
#pragma unroll
            for (int kt = 0; kt < 4; ++kt)
#pragma unroll
                for (int r = 0; r < 4; ++r) tm = fmaxf(tm, s[qs][kt][r]);
            tm = fmaxf(tm, __shfl_xor(tm, 16));
            tm = fmaxf(tm, __shfl_xor(tm, 32));
            if (!__all(tm <= mrun[qs] + 6.0f)) {
                const float mn = fmaxf(mrun[qs], tm);
                const float scal = __builtin_amdgcn_exp2f(mrun[qs] - mn);
                mrun[qs] = mn;
                lsum[qs] *= scal;
#pragma unroll
                for (int dt = 0; dt < 4; ++dt) {
                    acc[qs][dt][0] *= scal; acc[qs][dt][1] *= scal;
                    acc[qs][dt][2] *= scal; acc[qs][dt][3] *= scal;
                }
            }
            float ts = 0.f;
#pragma unroll
            for (int kt = 0; kt < 4; ++kt)
#pragma unroll
                for (int r = 0; r < 4; ++r) {
                    const float pv = __builtin_amdgcn_exp2f(s[qs][kt][r] - mrun[qs]);
                    ts += pv;
                    const int idx = kt * 4 + r;
                    if (idx < 8) po[qs][0][idx] = (bf16)pv;
                    else         po[qs][1][idx - 8] = (bf16)pv;
                }
            ts += __shfl_xor(ts, 16);
            ts += __shfl_xor(ts, 32);
            lsum[qs] += ts;
        }
        bf16x8 vb[4][2];
#pragma unroll
        for (int dt = 0; dt < 4; ++dt) {
            const int row = dt * 16 + l15;
            const int byte = (row * 128 + lg * 16) ^ ((row & 7) << 4);
            vb[dt][0] = *(const bf16x8*)((const char*)Vb[vcur] + byte);
            vb[dt][1] = *(const bf16x8*)((const char*)Vb[vcur] + (byte ^ 64));
        }
        __builtin_amdgcn_s_setprio(1);
#pragma unroll
        for (int qs = 0; qs < 2; ++qs)
#pragma unroll
            for (int dt = 0; dt < 4; ++dt) {
                acc[qs][dt] = __builtin_amdgcn_mfma_f32_16x16x32_bf16(vb[dt][0], po[qs][0], acc[qs][dt], 0, 0, 0);
                acc[qs][dt] = __builtin_amdgcn_mfma_f32_16x16x32_bf16(vb[dt][1], po[qs][1], acc[qs][dt], 0, 0, 0);
            }
        __builtin_amdgcn_s_setprio(0);
        if (t <= 13) asm volatile("s_waitcnt vmcnt(2)" ::: "memory");
        else         asm volatile("s_waitcnt vmcnt(0)" ::: "memory");
        __builtin_amdgcn_s_barrier();
    }
    // epilogue: O^T[d][q] -> per-wave LDS transpose (reuse Kb) -> coalesced stores
    char* scr = (char*)Kb + wid * 4096;
#pragma unroll
    for (int qs = 0; qs < 2; ++qs) {
        const float inv = 1.0f / lsum[qs];
        const int ql = qs * 16 + l15;
#pragma unroll
        for (int dt = 0; dt < 4; ++dt) {
            bf16x4 o;
#pragma unroll
            for (int r = 0; r < 4; ++r) o[r] = (bf16)(acc[qs][dt][r] * inv);
            const int wb = (ql * 128 + dt * 32 + lg * 8) ^ ((ql & 7) << 4);
            *(bf16x4*)(scr + wb) = o;
        }
    }
    __syncthreads();
#pragma unroll
    for (int qs = 0; qs < 2; ++qs) {
        const int ql = qs * 16 + l15;
        const int rb = (ql * 128 + lg * 32) ^ ((ql & 7) << 4);
        bf16x8 o0 = *(const bf16x8*)(scr + rb);
        bf16x8 o1 = *(const bf16x8*)(scr + (rb ^ 16));
        bf16* cp = ctx + (size_t)(b * 1024 + q0 + ql) * 768 + h * 64 + lg * 16;
        *(bf16x8*)cp = o0;
        *(bf16x8*)(cp + 8) = o1;
    }
}

// ---------------- layernorm ----------------
// MODE 0 (LN1): x bf16 + res f32 -> out bf16.
// MODE 1 (LN2): x bf16 + res bf16 -> out f32.
template<int MODE>
__global__ __launch_bounds__(256) void ln_kernel(const bf16* __restrict__ xb,
                                                 const float* __restrict__ resf,
                                                 const bf16* __restrict__ resb,
                                                 const float* __restrict__ g, const float* __restrict__ bt,
                                                 float* __restrict__ outf, bf16* __restrict__ outb) {
    const int wid = threadIdx.x >> 6, lane = threadIdx.x & 63;
    const int row = blockIdx.x * 4 + wid;
    float4 v[3];
    float s = 0.f, ss = 0.f;
#pragma unroll
    for (int j = 0; j < 3; ++j) {
        bf16x4 xa = ((const bf16x4*)(xb + (size_t)row * 768))[lane + 64 * j];
        float4 b;
        if (MODE == 0) {
            b = ((const float4*)(resf + (size_t)row * 768))[lane + 64 * j];
        } else {
            bf16x4 rb = ((const bf16x4*)(resb + (size_t)row * 768))[lane + 64 * j];
            b.x = (float)rb[0]; b.y = (float)rb[1]; b.z = (float)rb[2]; b.w = (float)rb[3];
        }
        float4 w;
        w.x = (float)xa[0] + b.x; w.y = (float)xa[1] + b.y;
        w.z = (float)xa[2] + b.z; w.w = (float)xa[3] + b.w;
        v[j] = w;
        s += w.x + w.y + w.z + w.w;
        ss += w.x * w.x + w.y * w.y + w.z * w.z + w.w * w.w;
    }
#pragma unroll
    for (int off = 1; off <= 32; off <<= 1) { s += __shfl_xor(s, off); ss += __shfl_xor(ss, off); }
    const float mean = s * (1.f / 768.f);
    float var = (ss - 768.f * mean * mean) * (1.f / 767.f);
    var = fmaxf(var, 0.f);
    const float inv = 1.f / (sqrtf(var) + 1e-6f);
#pragma unroll
    for (int j = 0; j < 3; ++j) {
        float4 gv = ((const float4*)g)[lane + 64 * j];
        float4 bv = ((const float4*)bt)[lane + 64 * j];
        float4 y;
        y.x = gv.x * (v[j].x - mean) * inv + bv.x;
        y.y = gv.y * (v[j].y - mean) * inv + bv.y;
        y.z = gv.z * (v[j].z - mean) * inv + bv.z;
        y.w = gv.w * (v[j].w - mean) * inv + bv.w;
        if (MODE == 1) {
            ((float4*)(outf + (size_t)row * 768))[lane + 64 * j] = y;
        } else {
            bf16x4 o;
            o[0] = (bf16)y.x; o[1] = (bf16)y.y; o[2] = (bf16)y.z; o[3] = (bf16)y.w;
            ((bf16x4*)(outb + (size_t)row * 768))[lane + 64 * j] = o;
        }
    }
}

// ---------------- launcher ----------------

extern "C" void kernel_launch(void* const* d_in, const int* in_sizes, int n_in,
                              void* d_out, int out_size, void* d_ws, size_t ws_size,
                              hipStream_t stream) {
    const float* hidden = (const float*)d_in[0];
    const float* mask   = (const float*)d_in[1];
    const float* pb     = (const float*)d_in[2];
    const float* Wq = (const float*)d_in[3];
    const float* bq = (const float*)d_in[4];
    const float* Wk = (const float*)d_in[5];
    const float* bk = (const float*)d_in[6];
    const float* Wv = (const float*)d_in[7];
    const float* bv = (const float*)d_in[8];
    const float* Wo = (const float*)d_in[9];
    const float* bo = (const float*)d_in[10];
    const float* W1 = (const float*)d_in[11];
    const float* b1 = (const float*)d_in[12];
    const float* W2 = (const float*)d_in[13];
    const float* b2 = (const float*)d_in[14];
    const float* g1  = (const float*)d_in[15];
    const float* be1 = (const float*)d_in[16];
    const float* g2  = (const float*)d_in[17];
    const float* be2 = (const float*)d_in[18];
    float* out = (float*)d_out;

    char* ws = (char*)d_ws;
    bf16*  xbf      = (bf16*)(ws);                       // 12,582,912 ; later inter_bf
    bf16*  wqkv_t   = (bf16*)(ws + 12582912);            // 3,538,944  [wq_t|wk_t|wv_t]
    bf16*  wo_t     = (bf16*)(ws + 16121856);            // 1,179,648
    bf16*  w1_t     = (bf16*)(ws + 17301504);            // 4,718,592
    bf16*  w2_t     = (bf16*)(ws + 22020096);            // 4,718,592
    float* bqk      = (float*)(ws + 26738688);           // 9,216
    bf16*  qk       = (bf16*)(ws + 26747904);            // 25,165,824 [8192][1536]
    bf16*  ffn1     = qk;                                // 50,331,648 span (qk+vT dead)
    bf16*  vT       = (bf16*)(ws + 26747904 + 25165824); // 12,582,912
    bf16*  ctx      = (bf16*)(ws + 77079552);            // 12,582,912
    bf16*  pbs      = (bf16*)(ws + 89662464);            // 25,165,824 (dead after attn)
    bf16*  attn_outb= (bf16*)(ws + 89662464);            // 12,582,912 (reuses pbs)
    bf16*  maskb    = (bf16*)(ws + 114828288);           // 16,777,216 (dead after attn)
    bf16*  ffn2b    = (bf16*)(ws + 114828288);           // 12,582,912 (reuses maskb)
    bf16*  interb   = xbf;
    bf16*  wv_t     = wqkv_t + 2 * 768 * 768;

    cast_bf16_kernel<<<6291456 / 4 / 256, 256, 0, stream>>>(hidden, xbf, 6291456 / 4);
    tcast_kernel<<<dim3(24, 24), 256, 0, stream>>>(Wq, wqkv_t, 768, 768);
    tcast_kernel<<<dim3(24, 24), 256, 0, stream>>>(Wk, wqkv_t + 768 * 768, 768, 768);
    tcast_kernel<<<dim3(24, 24), 256, 0, stream>>>(Wv, wv_t, 768, 768);
    tcast_kernel<<<dim3(24, 24), 256, 0, stream>>>(Wo, wo_t, 768, 768);
    tcast_kernel<<<dim3(96, 24), 256, 0, stream>>>(W1, w1_t, 768, 3072);
    tcast_kernel<<<dim3(24, 96), 256, 0, stream>>>(W2, w2_t, 3072, 768);
    concat_bias_kernel<<<6, 256, 0, stream>>>(bq, bk, bqk);
    prep_pm_kernel<<<(3145728 + 2097152) / 256, 256, 0, stream>>>(pb, mask, pbs, maskb,
                                                                  3145728, 2097152);

    gemm_kernel<0, 128><<<dim3(12, 64), 256, 0, stream>>>(xbf, wqkv_t, bqk, qk, 8192, 1536, 768, 1536);
    gemm_kernel<3, 128><<<dim3(64, 6), 256, 0, stream>>>(wv_t, xbf, bv, vT, 768, 8192, 768, 0);
    attn_kernel<<<dim3(8, 96), 256, 0, stream>>>(qk, pbs, maskb, vT, ctx);
    gemm_kernel<0, 64><<<dim3(12, 64), 256, 0, stream>>>(ctx, wo_t, bo, attn_outb, 8192, 768, 768, 768);
    ln_kernel<0><<<2048, 256, 0, stream>>>(attn_outb, hidden, nullptr, g1, be1, nullptr, interb);
    gemm_kernel<2, 128><<<dim3(24, 64), 256, 0, stream>>>(interb, w1_t, b1, ffn1, 8192, 3072, 768, 3072);
    gemm_kernel<0, 64><<<dim3(12, 64), 256, 0, stream>>>(ffn1, w2_t, b2, ffn2b, 8192, 768, 3072, 768);
    ln_kernel<1><<<2048, 256, 0, stream>>>(ffn2b, nullptr, interb, g2, be2, out, nullptr);
}

// Round 14
// 298.523 us; speedup vs baseline: 1.3836x; 1.3836x over previous
//
#include <hip/hip_runtime.h>
#include <cmath>

typedef __bf16 bf16;
typedef __attribute__((ext_vector_type(8))) __bf16 bf16x8;
typedef __attribute__((ext_vector_type(4))) __bf16 bf16x4;
typedef __attribute__((ext_vector_type(4))) float f32x4;

#define DEVINL __device__ __forceinline__

DEVINL void gload16(const void* g, void* l) {
    __builtin_amdgcn_global_load_lds((const __attribute__((address_space(1))) void*)g,
                                     (__attribute__((address_space(3))) void*)l, 16, 0, 0);
}

// ---------------- utility kernels ----------------

__global__ void cast_bf16_kernel(const float* __restrict__ in, bf16* __restrict__ out, int n4) {
    int i = blockIdx.x * 256 + threadIdx.x;
    if (i < n4) {
        float4 v = ((const float4*)in)[i];
        bf16x4 o;
        o[0] = (bf16)v.x; o[1] = (bf16)v.y; o[2] = (bf16)v.z; o[3] = (bf16)v.w;
        ((bf16x4*)out)[i] = o;
    }
}

// pb*0.125*log2e -> bf16 ; mask*log2e -> bf16 ; bq|bk concat -> f32 (one launch)
__global__ void prep_pm_kernel(const float* __restrict__ pb, const float* __restrict__ mask,
                               const float* __restrict__ bq, const float* __restrict__ bk,
                               bf16* __restrict__ pbs, bf16* __restrict__ maskb,
                               float* __restrict__ bqk, int n1, int n2) {
    const int i = blockIdx.x * 256 + threadIdx.x;
    const float c1 = 0.18033688011112042f;   // 0.125 * log2(e)
    const float c2 = 1.4426950408889634f;    // log2(e)
    if (i < n1) {
        float4 v = ((const float4*)pb)[i];
        bf16x4 o;
        o[0] = (bf16)(v.x * c1); o[1] = (bf16)(v.y * c1);
        o[2] = (bf16)(v.z * c1); o[3] = (bf16)(v.w * c1);
        ((bf16x4*)pbs)[i] = o;
    } else if (i < n1 + n2) {
        const int j = i - n1;
        float4 v = ((const float4*)mask)[j];
        bf16x4 o;
        o[0] = (bf16)(v.x * c2); o[1] = (bf16)(v.y * c2);
        o[2] = (bf16)(v.z * c2); o[3] = (bf16)(v.w * c2);
        ((bf16x4*)maskb)[j] = o;
    } else if (i < n1 + n2 + 384) {
        const int j = i - n1 - n2;
        float4 o = (j < 192) ? ((const float4*)bq)[j] : ((const float4*)bk)[j - 192];
        ((float4*)bqk)[j] = o;
    }
}

// in: [R][C] f32  ->  out: [C][R] bf16
__global__ void tcast_kernel(const float* __restrict__ in, bf16* __restrict__ out, int R, int C) {
    __shared__ float t[32][33];
    int tx = threadIdx.x & 31, ty = threadIdx.x >> 5;
    int r0 = blockIdx.y * 32, c0 = blockIdx.x * 32;
#pragma unroll
    for (int i = 0; i < 4; ++i)
        t[ty + 8 * i][tx] = in[(size_t)(r0 + ty + 8 * i) * C + c0 + tx];
    __syncthreads();
#pragma unroll
    for (int i = 0; i < 4; ++i)
        out[(size_t)(c0 + ty + 8 * i) * R + r0 + tx] = (bf16)t[tx][ty + 8 * i];
}

// four 768x768 transposes in one launch (blockIdx.z selects matrix)
__global__ void tcast4_kernel(const float* __restrict__ w0, const float* __restrict__ w1,
                              const float* __restrict__ w2, const float* __restrict__ w3,
                              bf16* __restrict__ o0, bf16* __restrict__ o1,
                              bf16* __restrict__ o2, bf16* __restrict__ o3) {
    __shared__ float t[32][33];
    const int z = blockIdx.z;
    const float* in = (z == 0) ? w0 : (z == 1) ? w1 : (z == 2) ? w2 : w3;
    bf16* out = (z == 0) ? o0 : (z == 1) ? o1 : (z == 2) ? o2 : o3;
    int tx = threadIdx.x & 31, ty = threadIdx.x >> 5;
    int r0 = blockIdx.y * 32, c0 = blockIdx.x * 32;
#pragma unroll
    for (int i = 0; i < 4; ++i)
        t[ty + 8 * i][tx] = in[(size_t)(r0 + ty + 8 * i) * 768 + c0 + tx];
    __syncthreads();
#pragma unroll
    for (int i = 0; i < 4; ++i)
        out[(size_t)(c0 + ty + 8 * i) * 768 + r0 + tx] = (bf16)t[tx][ty + 8 * i];
}

// ---------------- GEMM: C[M][N] = A[M][K] * Bt[N][K]^T + bias ----------------
// 128 x BN tile, 4 waves, single-buffered LDS, TLP-hidden staging (proven
// round-4 structure). MODE 0: bias[col]->bf16 row-major; MODE 2: +gelu;
// MODE 3: bias[row], store into vT layout ((col>>10)*768+row)*1024+(col&1023).
// T1 XCD swizzle (grid %8==0).
template<int MODE, int BN>
__global__ __launch_bounds__(256, 4) void gemm_kernel(const bf16* __restrict__ A, const bf16* __restrict__ Bt,
                                                      const float* __restrict__ bias,
                                                      bf16* __restrict__ Cb,
                                                      int M, int N, int K, int ldc) {
    constexpr int NI = BN / 32;
    constexpr int BLOADS = BN / 32;
    __shared__ __align__(16) bf16 As[128 * 64];
    __shared__ __align__(16) bf16 Bs[BN * 64];
    const int tid = threadIdx.x;
    const int wid = tid >> 6, lane = tid & 63;
    const int L = blockIdx.y * gridDim.x + blockIdx.x;
    const int cpx = (gridDim.x * gridDim.y) >> 3;
    const int wg = (L & 7) * cpx + (L >> 3);
    const int m0 = (wg / gridDim.x) * 128, n0 = (wg % gridDim.x) * BN;
    const int wr = (wid >> 1) * 64, wc = (wid & 1) * (BN / 2);
    const int lg = lane >> 4, l15 = lane & 15;
    f32x4 acc[4][NI] = {};

    for (int k0 = 0; k0 < K; k0 += 64) {
        __syncthreads();
#pragma unroll
        for (int i = 0; i < 4; ++i) {
            const int cbase = (wid * 4 + i) * 1024;
            const int td = cbase + lane * 16;
            const int row = td >> 7;
            const int s16 = ((td >> 4) & 7) ^ (row & 7);
            gload16(A + (size_t)(m0 + row) * K + k0 + s16 * 8, (char*)As + cbase);
        }
#pragma unroll
        for (int i = 0; i < BLOADS; ++i) {
            const int cbase = (wid * BLOADS + i) * 1024;
            const int td = cbase + lane * 16;
            const int row = td >> 7;
            const int s16 = ((td >> 4) & 7) ^ (row & 7);
            gload16(Bt + (size_t)(n0 + row) * K + k0 + s16 * 8, (char*)Bs + cbase);
        }
        __syncthreads();
#pragma unroll
        for (int kk = 0; kk < 2; ++kk) {
            bf16x8 af[4], bfr[NI];
#pragma unroll
            for (int mi = 0; mi < 4; ++mi) {
                int ra = wr + mi * 16 + l15;
                int off = (ra * 128 + (kk * 32 + 8 * lg) * 2) ^ ((ra & 7) << 4);
                af[mi] = *(const bf16x8*)((const char*)As + off);
            }
#pragma unroll
            for (int ni = 0; ni < NI; ++ni) {
                int rb = wc + ni * 16 + l15;
                int off = (rb * 128 + (kk * 32 + 8 * lg) * 2) ^ ((rb & 7) << 4);
                bfr[ni] = *(const bf16x8*)((const char*)Bs + off);
            }
#pragma unroll
            for (int mi = 0; mi < 4; ++mi)
#pragma unroll
                for (int ni = 0; ni < NI; ++ni)
                    acc[mi][ni] = __builtin_amdgcn_mfma_f32_16x16x32_bf16(af[mi], bfr[ni], acc[mi][ni], 0, 0, 0);
        }
    }
#pragma unroll
    for (int mi = 0; mi < 4; ++mi) {
#pragma unroll
        for (int r = 0; r < 4; ++r) {
            const int row = m0 + wr + mi * 16 + lg * 4 + r;
#pragma unroll
            for (int ni = 0; ni < NI; ++ni) {
                const int col = n0 + wc + ni * 16 + l15;
                float v = acc[mi][ni][r] + bias[(MODE == 3) ? row : col];
                if (MODE == 2) v = v * 0.5f * (1.0f + erff(v * 0.70710678118654752f));
                if (MODE == 3)
                    Cb[((size_t)(col >> 10) * 768 + row) * 1024 + (col & 1023)] = (bf16)v;
                else
                    Cb[(size_t)row * ldc + col] = (bf16)v;
            }
        }
    }
}

// ---------------- flash attention (round-11 proven: 74.4 us) ----------------
// qk: [8192][1536] bf16 (Q|K per head); vT: [96][64][1024]; grid (8 qb, 96 bh).
// K LDS rows permuted by phys(i)=bits [i5][i3][i2][i4][i1][i0] so the QK^T
// per-lane k-set equals the PV B-fragment layout; P stays in registers.
// Counted-vmcnt barriers (T4): s_waitcnt vmcnt(4) + raw s_barrier keeps the
// newest stage (t+2, 4 loads/thread) in flight across the barrier; stage(t+1)
// drains only at the END of tile t -> a full tile of staging-latency cover.
// T5 setprio wraps MFMA clusters. pb/mask loaded inline (r8/r9: reg-prefetch
// is refused by regalloc and doubles FETCH).
__global__ __launch_bounds__(256, 3) void attn_kernel(const bf16* __restrict__ qk,
                                                      const bf16* __restrict__ pbs,
                                                      const bf16* __restrict__ maskb,
                                                      const bf16* __restrict__ vT,
                                                      bf16* __restrict__ ctx) {
    __shared__ __align__(16) bf16 Kb[3][64 * 64];
    __shared__ __align__(16) bf16 Vb[3][64 * 64];
    const int tid = threadIdx.x, wid = tid >> 6, lane = tid & 63;
    const int bh = blockIdx.y, b = bh / 12, h = bh % 12;
    const int q0 = blockIdx.x * 128 + wid * 32;
    const int lg = lane >> 4, l15 = lane & 15;
    const float cqk = 0.18033688011112042f;  // 0.125 * log2(e)

    bf16x8 aq[2][2];
#pragma unroll
    for (int qs = 0; qs < 2; ++qs) {
        const size_t r = (size_t)(b * 1024 + q0 + qs * 16 + l15) * 1536 + h * 64 + 8 * lg;
        aq[qs][0] = *(const bf16x8*)(qk + r);
        aq[qs][1] = *(const bf16x8*)(qk + r + 32);
    }

    auto stage = [&](int tt, int pp) {
#pragma unroll
        for (int rd = 0; rd < 2; ++rd) {
            const int n = rd * 256 + tid;
            const int i = n >> 3, sl = n & 7, c = sl ^ (i & 7);
            const int sig = (i & 32) | ((i & 12) << 1) | ((i & 16) >> 2) | (i & 3);
            gload16(qk + (size_t)(b * 1024 + tt * 64 + sig) * 1536 + 768 + h * 64 + c * 8,
                    (char*)Kb[pp] + (rd * 256 + wid * 64) * 16);
            gload16(vT + ((size_t)bh * 64 + i) * 1024 + tt * 64 + c * 8,
                    (char*)Vb[pp] + (rd * 256 + wid * 64) * 16);
        }
    };

    float mrun[2] = {-1e30f, -1e30f}, lsum[2] = {0.f, 0.f};
    f32x4 acc[2][4] = {};

    stage(0, 0);
    stage(1, 1);
    asm volatile("s_waitcnt vmcnt(4)" ::: "memory");
    __builtin_amdgcn_s_barrier();
    for (int t = 0; t < 16; ++t) {
        const int p = t % 3;
        const int k0 = t * 64;
        bf16x8 pbv[2][2], mkv[2][2];
#pragma unroll
        for (int qs = 0; qs < 2; ++qs) {
            const int q = q0 + qs * 16 + l15;
            const bf16* pr = pbs + ((size_t)h * 1024 + q) * 1024 + k0 + lg * 8;
            const bf16* mr = maskb + ((size_t)b * 1024 + q) * 1024 + k0 + lg * 8;
            pbv[qs][0] = *(const bf16x8*)pr;  pbv[qs][1] = *(const bf16x8*)(pr + 32);
            mkv[qs][0] = *(const bf16x8*)mr;  mkv[qs][1] = *(const bf16x8*)(mr + 32);
        }
        if (t < 14) stage(t + 2, (t + 2) % 3);

        bf16x8 bk[4][2];
#pragma unroll
        for (int kt = 0; kt < 4; ++kt) {
            const int row = kt * 16 + l15;
            const int byte = (row * 128 + lg * 16) ^ ((row & 7) << 4);
            bk[kt][0] = *(const bf16x8*)((const char*)Kb[p] + byte);
            bk[kt][1] = *(const bf16x8*)((const char*)Kb[p] + (byte ^ 64));
        }
        f32x4 s[2][4];
        __builtin_amdgcn_s_setprio(1);
#pragma unroll
        for (int qs = 0; qs < 2; ++qs)
#pragma unroll
            for (int kt = 0; kt < 4; ++kt) {
                f32x4 z = {};
                z = __builtin_amdgcn_mfma_f32_16x16x32_bf16(bk[kt][0], aq[qs][0], z, 0, 0, 0);
                z = __builtin_amdgcn_mfma_f32_16x16x32_bf16(bk[kt][1], aq[qs][1], z, 0, 0, 0);
                s[qs][kt] = z;
            }
        __builtin_amdgcn_s_setprio(0);
#pragma unroll
        for (int qs = 0; qs < 2; ++qs)
#pragma unroll
            for (int kt = 0; kt < 4; ++kt)
#pragma unroll
                for (int r = 0; r < 4; ++r) {
                    const int j = (kt & 1) * 4 + r;
                    s[qs][kt][r] = s[qs][kt][r] * cqk
                                 + (float)pbv[qs][kt >> 1][j]
                                 + (float)mkv[qs][kt >> 1][j];
                }
        // online softmax with defer-max (T13): skip rescale while growth <= 6
        bf16x8 po[2][2];
#pragma unroll
        for (int qs = 0; qs < 2; ++qs) {
            float tm = s[qs][0][0];
#pragma unroll
            for (int kt = 0; kt < 4; ++kt)
#pragma unroll
                for (int r = 0; r < 4; ++r) tm = fmaxf(tm, s[qs][kt][r]);
            tm = fmaxf(tm, __shfl_xor(tm, 16));
            tm = fmaxf(tm, __shfl_xor(tm, 32));
            if (!__all(tm <= mrun[qs] + 6.0f)) {
                const float mn = fmaxf(mrun[qs], tm);
                const float scal = __builtin_amdgcn_exp2f(mrun[qs] - mn);
                mrun[qs] = mn;
                lsum[qs] *= scal;
#pragma unroll
                for (int dt = 0; dt < 4; ++dt) {
                    acc[qs][dt][0] *= scal; acc[qs][dt][1] *= scal;
                    acc[qs][dt][2] *= scal; acc[qs][dt][3] *= scal;
                }
            }
            float ts = 0.f;
#pragma unroll
            for (int kt = 0; kt < 4; ++kt)
#pragma unroll
                for (int r = 0; r < 4; ++r) {
                    const float pv = __builtin_amdgcn_exp2f(s[qs][kt][r] - mrun[qs]);
                    ts += pv;
                    const int idx = kt * 4 + r;
                    if (idx < 8) po[qs][0][idx] = (bf16)pv;
                    else         po[qs][1][idx - 8] = (bf16)pv;
                }
            ts += __shfl_xor(ts, 16);
            ts += __shfl_xor(ts, 32);
            lsum[qs] += ts;
        }
        bf16x8 vb[4][2];
#pragma unroll
        for (int dt = 0; dt < 4; ++dt) {
            const int row = dt * 16 + l15;
            const int byte = (row * 128 + lg * 16) ^ ((row & 7) << 4);
            vb[dt][0] = *(const bf16x8*)((const char*)Vb[p] + byte);
            vb[dt][1] = *(const bf16x8*)((const char*)Vb[p] + (byte ^ 64));
        }
        __builtin_amdgcn_s_setprio(1);
#pragma unroll
        for (int qs = 0; qs < 2; ++qs)
#pragma unroll
            for (int dt = 0; dt < 4; ++dt) {
                acc[qs][dt] = __builtin_amdgcn_mfma_f32_16x16x32_bf16(vb[dt][0], po[qs][0], acc[qs][dt], 0, 0, 0);
                acc[qs][dt] = __builtin_amdgcn_mfma_f32_16x16x32_bf16(vb[dt][1], po[qs][1], acc[qs][dt], 0, 0, 0);
            }
        __builtin_amdgcn_s_setprio(0);
        asm volatile("s_waitcnt vmcnt(4)" ::: "memory");
        __builtin_amdgcn_s_barrier();
    }
    // epilogue: O^T[d][q] -> per-wave LDS transpose (reuse Kb) -> coalesced stores
    char* scr = (char*)Kb + wid * 4096;
#pragma unroll
    for (int qs = 0; qs < 2; ++qs) {
        const float inv = 1.0f / lsum[qs];
        const int ql = qs * 16 + l15;
#pragma unroll
        for (int dt = 0; dt < 4; ++dt) {
            bf16x4 o;
#pragma unroll
            for (int r = 0; r < 4; ++r) o[r] = (bf16)(acc[qs][dt][r] * inv);
            const int wb = (ql * 128 + dt * 32 + lg * 8) ^ ((ql & 7) << 4);
            *(bf16x4*)(scr + wb) = o;
        }
    }
    __syncthreads();
#pragma unroll
    for (int qs = 0; qs < 2; ++qs) {
        const int ql = qs * 16 + l15;
        const int rb = (ql * 128 + lg * 32) ^ ((ql & 7) << 4);
        bf16x8 o0 = *(const bf16x8*)(scr + rb);
        bf16x8 o1 = *(const bf16x8*)(scr + (rb ^ 16));
        bf16* cp = ctx + (size_t)(b * 1024 + q0 + ql) * 768 + h * 64 + lg * 16;
        *(bf16x8*)cp = o0;
        *(bf16x8*)(cp + 8) = o1;
    }
}

// ---------------- layernorm ----------------
// MODE 0 (LN1): x bf16 + res f32 -> out bf16.
// MODE 1 (LN2): x bf16 + res bf16 -> out f32.
template<int MODE>
__global__ __launch_bounds__(256) void ln_kernel(const bf16* __restrict__ xb,
                                                 const float* __restrict__ resf,
                                                 const bf16* __restrict__ resb,
                                                 const float* __restrict__ g, const float* __restrict__ bt,
                                                 float* __restrict__ outf, bf16* __restrict__ outb) {
    const int wid = threadIdx.x >> 6, lane = threadIdx.x & 63;
    const int row = blockIdx.x * 4 + wid;
    float4 v[3];
    float s = 0.f, ss = 0.f;
#pragma unroll
    for (int j = 0; j < 3; ++j) {
        bf16x4 xa = ((const bf16x4*)(xb + (size_t)row * 768))[lane + 64 * j];
        float4 b;
        if (MODE == 0) {
            b = ((const float4*)(resf + (size_t)row * 768))[lane + 64 * j];
        } else {
            bf16x4 rb = ((const bf16x4*)(resb + (size_t)row * 768))[lane + 64 * j];
            b.x = (float)rb[0]; b.y = (float)rb[1]; b.z = (float)rb[2]; b.w = (float)rb[3];
        }
        float4 w;
        w.x = (float)xa[0] + b.x; w.y = (float)xa[1] + b.y;
        w.z = (float)xa[2] + b.z; w.w = (float)xa[3] + b.w;
        v[j] = w;
        s += w.x + w.y + w.z + w.w;
        ss += w.x * w.x + w.y * w.y + w.z * w.z + w.w * w.w;
    }
#pragma unroll
    for (int off = 1; off <= 32; off <<= 1) { s += __shfl_xor(s, off); ss += __shfl_xor(ss, off); }
    const float mean = s * (1.f / 768.f);
    float var = (ss - 768.f * mean * mean) * (1.f / 767.f);
    var = fmaxf(var, 0.f);
    const float inv = 1.f / (sqrtf(var) + 1e-6f);
#pragma unroll
    for (int j = 0; j < 3; ++j) {
        float4 gv = ((const float4*)g)[lane + 64 * j];
        float4 bv = ((const float4*)bt)[lane + 64 * j];
        float4 y;
        y.x = gv.x * (v[j].x - mean) * inv + bv.x;
        y.y = gv.y * (v[j].y - mean) * inv + bv.y;
        y.z = gv.z * (v[j].z - mean) * inv + bv.z;
        y.w = gv.w * (v[j].w - mean) * inv + bv.w;
        if (MODE == 1) {
            ((float4*)(outf + (size_t)row * 768))[lane + 64 * j] = y;
        } else {
            bf16x4 o;
            o[0] = (bf16)y.x; o[1] = (bf16)y.y; o[2] = (bf16)y.z; o[3] = (bf16)y.w;
            ((bf16x4*)(outb + (size_t)row * 768))[lane + 64 * j] = o;
        }
    }
}

// ---------------- launcher ----------------

extern "C" void kernel_launch(void* const* d_in, const int* in_sizes, int n_in,
                              void* d_out, int out_size, void* d_ws, size_t ws_size,
                              hipStream_t stream) {
    const float* hidden = (const float*)d_in[0];
    const float* mask   = (const float*)d_in[1];
    const float* pb     = (const float*)d_in[2];
    const float* Wq = (const float*)d_in[3];
    const float* bq = (const float*)d_in[4];
    const float* Wk = (const float*)d_in[5];
    const float* bk = (const float*)d_in[6];
    const float* Wv = (const float*)d_in[7];
    const float* bv = (const float*)d_in[8];
    const float* Wo = (const float*)d_in[9];
    const float* bo = (const float*)d_in[10];
    const float* W1 = (const float*)d_in[11];
    const float* b1 = (const float*)d_in[12];
    const float* W2 = (const float*)d_in[13];
    const float* b2 = (const float*)d_in[14];
    const float* g1  = (const float*)d_in[15];
    const float* be1 = (const float*)d_in[16];
    const float* g2  = (const float*)d_in[17];
    const float* be2 = (const float*)d_in[18];
    float* out = (float*)d_out;

    char* ws = (char*)d_ws;
    bf16*  xbf      = (bf16*)(ws);                       // 12,582,912 ; later inter_bf
    bf16*  wqkv_t   = (bf16*)(ws + 12582912);            // 3,538,944  [wq_t|wk_t|wv_t]
    bf16*  wo_t     = (bf16*)(ws + 16121856);            // 1,179,648
    bf16*  w1_t     = (bf16*)(ws + 17301504);            // 4,718,592
    bf16*  w2_t     = (bf16*)(ws + 22020096);            // 4,718,592
    float* bqk      = (float*)(ws + 26738688);           // 9,216
    bf16*  qk       = (bf16*)(ws + 26747904);            // 25,165,824 [8192][1536]
    bf16*  ffn1     = qk;                                // 50,331,648 span (qk+vT dead)
    bf16*  vT       = (bf16*)(ws + 26747904 + 25165824); // 12,582,912
    bf16*  ctx      = (bf16*)(ws + 77079552);            // 12,582,912
    bf16*  pbs      = (bf16*)(ws + 89662464);            // 25,165,824 (dead after attn)
    bf16*  attn_outb= (bf16*)(ws + 89662464);            // 12,582,912 (reuses pbs)
    bf16*  maskb    = (bf16*)(ws + 114828288);           // 16,777,216 (dead after attn)
    bf16*  ffn2b    = (bf16*)(ws + 114828288);           // 12,582,912 (reuses maskb)
    bf16*  interb   = xbf;
    bf16*  wv_t     = wqkv_t + 2 * 768 * 768;

    cast_bf16_kernel<<<6291456 / 4 / 256, 256, 0, stream>>>(hidden, xbf, 6291456 / 4);
    tcast4_kernel<<<dim3(24, 24, 4), 256, 0, stream>>>(Wq, Wk, Wv, Wo,
                                                       wqkv_t, wqkv_t + 768 * 768, wv_t, wo_t);
    tcast_kernel<<<dim3(96, 24), 256, 0, stream>>>(W1, w1_t, 768, 3072);
    tcast_kernel<<<dim3(24, 96), 256, 0, stream>>>(W2, w2_t, 3072, 768);
    prep_pm_kernel<<<20482, 256, 0, stream>>>(pb, mask, bq, bk, pbs, maskb, bqk,
                                              3145728, 2097152);

    gemm_kernel<0, 128><<<dim3(12, 64), 256, 0, stream>>>(xbf, wqkv_t, bqk, qk, 8192, 1536, 768, 1536);
    gemm_kernel<3, 128><<<dim3(64, 6), 256, 0, stream>>>(wv_t, xbf, bv, vT, 768, 8192, 768, 0);
    attn_kernel<<<dim3(8, 96), 256, 0, stream>>>(qk, pbs, maskb, vT, ctx);
    gemm_kernel<0, 64><<<dim3(12, 64), 256, 0, stream>>>(ctx, wo_t, bo, attn_outb, 8192, 768, 768, 768);
    ln_kernel<0><<<2048, 256, 0, stream>>>(attn_outb, hidden, nullptr, g1, be1, nullptr, interb);
    gemm_kernel<2, 128><<<dim3(24, 64), 256, 0, stream>>>(interb, w1_t, b1, ffn1, 8192, 3072, 768, 3072);
    gemm_kernel<0, 64><<<dim3(12, 64), 256, 0, stream>>>(ffn1, w2_t, b2, ffn2b, 8192, 768, 3072, 768);
    ln_kernel<1><<<2048, 256, 0, stream>>>(ffn2b, nullptr, interb, g2, be2, out, nullptr);
}

// Round 15
// 289.518 us; speedup vs baseline: 1.4267x; 1.0311x over previous
//
#include <hip/hip_runtime.h>
#include <cmath>

typedef __bf16 bf16;
typedef __attribute__((ext_vector_type(8))) __bf16 bf16x8;
typedef __attribute__((ext_vector_type(4))) __bf16 bf16x4;
typedef __attribute__((ext_vector_type(4))) float f32x4;

#define DEVINL __device__ __forceinline__

DEVINL void gload16(const void* g, void* l) {
    __builtin_amdgcn_global_load_lds((const __attribute__((address_space(1))) void*)g,
                                     (__attribute__((address_space(3))) void*)l, 16, 0, 0);
}

// ---------------- fused prep kernel ----------------
// One launch does: hidden f32->bf16 cast (6144 blocks), Wq/Wk/Wv/Wo 768x768
// transpose-casts (2304), W1 tcast (2304), W2 tcast (2304), pb/mask scale-cast
// + bias concat (20482). Total 33838 blocks.
__global__ __launch_bounds__(256) void prep_all_kernel(
        const float* __restrict__ hidden, bf16* __restrict__ xbf,
        const float* __restrict__ Wq, const float* __restrict__ Wk,
        const float* __restrict__ Wv, const float* __restrict__ Wo,
        bf16* __restrict__ wq_t, bf16* __restrict__ wk_t,
        bf16* __restrict__ wv_t, bf16* __restrict__ wo_t,
        const float* __restrict__ W1, bf16* __restrict__ w1_t,
        const float* __restrict__ W2, bf16* __restrict__ w2_t,
        const float* __restrict__ pb, const float* __restrict__ mask,
        const float* __restrict__ bq, const float* __restrict__ bk,
        bf16* __restrict__ pbs, bf16* __restrict__ maskb, float* __restrict__ bqk) {
    const int bid = blockIdx.x;
    const int tid = threadIdx.x;
    if (bid < 6144) {                              // hidden cast (float4 per thread)
        const int i = bid * 256 + tid;
        float4 v = ((const float4*)hidden)[i];
        bf16x4 o;
        o[0] = (bf16)v.x; o[1] = (bf16)v.y; o[2] = (bf16)v.z; o[3] = (bf16)v.w;
        ((bf16x4*)xbf)[i] = o;
        return;
    }
    if (bid < 6144 + 3 * 2304) {                   // transposes (all use LDS tile)
        __shared__ float t[32][33];
        const int tx = tid & 31, ty = tid >> 5;
        const float* in; bf16* out; int R, C, r0, c0;
        if (bid < 6144 + 2304) {                   // 4x 768x768 (z = local/576)
            const int local = bid - 6144;
            const int z = local / 576, rem = local % 576;
            in  = (z == 0) ? Wq : (z == 1) ? Wk : (z == 2) ? Wv : Wo;
            out = (z == 0) ? wq_t : (z == 1) ? wk_t : (z == 2) ? wv_t : wo_t;
            R = 768; C = 768; c0 = (rem % 24) * 32; r0 = (rem / 24) * 32;
        } else if (bid < 6144 + 2 * 2304) {        // W1: R=768, C=3072 (96x24)
            const int local = bid - 6144 - 2304;
            in = W1; out = w1_t; R = 768; C = 3072;
            c0 = (local % 96) * 32; r0 = (local / 96) * 32;
        } else {                                   // W2: R=3072, C=768 (24x96)
            const int local = bid - 6144 - 2 * 2304;
            in = W2; out = w2_t; R = 3072; C = 768;
            c0 = (local % 24) * 32; r0 = (local / 24) * 32;
        }
#pragma unroll
        for (int i = 0; i < 4; ++i)
            t[ty + 8 * i][tx] = in[(size_t)(r0 + ty + 8 * i) * C + c0 + tx];
        __syncthreads();
#pragma unroll
        for (int i = 0; i < 4; ++i)
            out[(size_t)(c0 + ty + 8 * i) * R + r0 + tx] = (bf16)t[tx][ty + 8 * i];
        return;
    }
    // pb/mask scale-cast + bias concat
    const int i = (bid - 6144 - 3 * 2304) * 256 + tid;
    const int n1 = 3145728, n2 = 2097152;
    const float c1 = 0.18033688011112042f;   // 0.125 * log2(e)
    const float c2 = 1.4426950408889634f;    // log2(e)
    if (i < n1) {
        float4 v = ((const float4*)pb)[i];
        bf16x4 o;
        o[0] = (bf16)(v.x * c1); o[1] = (bf16)(v.y * c1);
        o[2] = (bf16)(v.z * c1); o[3] = (bf16)(v.w * c1);
        ((bf16x4*)pbs)[i] = o;
    } else if (i < n1 + n2) {
        const int j = i - n1;
        float4 v = ((const float4*)mask)[j];
        bf16x4 o;
        o[0] = (bf16)(v.x * c2); o[1] = (bf16)(v.y * c2);
        o[2] = (bf16)(v.z * c2); o[3] = (bf16)(v.w * c2);
        ((bf16x4*)maskb)[j] = o;
    } else if (i < n1 + n2 + 384) {
        const int j = i - n1 - n2;
        float4 o = (j < 192) ? ((const float4*)bq)[j] : ((const float4*)bk)[j - 192];
        ((float4*)bqk)[j] = o;
    }
}

// ---------------- GEMM: C[M][N] = A[M][K] * Bt[N][K]^T + bias ----------------
// 128 x BN tile, 4 waves, single-buffered LDS, TLP-hidden staging (proven
// round-4 structure). MODE 0: bias[col]->bf16 row-major; MODE 2: +gelu;
// MODE 3: bias[row], store into vT layout ((col>>10)*768+row)*1024+(col&1023).
// T1 XCD swizzle (grid %8==0).
template<int MODE, int BN>
__global__ __launch_bounds__(256, 4) void gemm_kernel(const bf16* __restrict__ A, const bf16* __restrict__ Bt,
                                                      const float* __restrict__ bias,
                                                      bf16* __restrict__ Cb,
                                                      int M, int N, int K, int ldc) {
    constexpr int NI = BN / 32;
    constexpr int BLOADS = BN / 32;
    __shared__ __align__(16) bf16 As[128 * 64];
    __shared__ __align__(16) bf16 Bs[BN * 64];
    const int tid = threadIdx.x;
    const int wid = tid >> 6, lane = tid & 63;
    const int L = blockIdx.y * gridDim.x + blockIdx.x;
    const int cpx = (gridDim.x * gridDim.y) >> 3;
    const int wg = (L & 7) * cpx + (L >> 3);
    const int m0 = (wg / gridDim.x) * 128, n0 = (wg % gridDim.x) * BN;
    const int wr = (wid >> 1) * 64, wc = (wid & 1) * (BN / 2);
    const int lg = lane >> 4, l15 = lane & 15;
    f32x4 acc[4][NI] = {};

    for (int k0 = 0; k0 < K; k0 += 64) {
        __syncthreads();
#pragma unroll
        for (int i = 0; i < 4; ++i) {
            const int cbase = (wid * 4 + i) * 1024;
            const int td = cbase + lane * 16;
            const int row = td >> 7;
            const int s16 = ((td >> 4) & 7) ^ (row & 7);
            gload16(A + (size_t)(m0 + row) * K + k0 + s16 * 8, (char*)As + cbase);
        }
#pragma unroll
        for (int i = 0; i < BLOADS; ++i) {
            const int cbase = (wid * BLOADS + i) * 1024;
            const int td = cbase + lane * 16;
            const int row = td >> 7;
            const int s16 = ((td >> 4) & 7) ^ (row & 7);
            gload16(Bt + (size_t)(n0 + row) * K + k0 + s16 * 8, (char*)Bs + cbase);
        }
        __syncthreads();
#pragma unroll
        for (int kk = 0; kk < 2; ++kk) {
            bf16x8 af[4], bfr[NI];
#pragma unroll
            for (int mi = 0; mi < 4; ++mi) {
                int ra = wr + mi * 16 + l15;
                int off = (ra * 128 + (kk * 32 + 8 * lg) * 2) ^ ((ra & 7) << 4);
                af[mi] = *(const bf16x8*)((const char*)As + off);
            }
#pragma unroll
            for (int ni = 0; ni < NI; ++ni) {
                int rb = wc + ni * 16 + l15;
                int off = (rb * 128 + (kk * 32 + 8 * lg) * 2) ^ ((rb & 7) << 4);
                bfr[ni] = *(const bf16x8*)((const char*)Bs + off);
            }
#pragma unroll
            for (int mi = 0; mi < 4; ++mi)
#pragma unroll
                for (int ni = 0; ni < NI; ++ni)
                    acc[mi][ni] = __builtin_amdgcn_mfma_f32_16x16x32_bf16(af[mi], bfr[ni], acc[mi][ni], 0, 0, 0);
        }
    }
#pragma unroll
    for (int mi = 0; mi < 4; ++mi) {
#pragma unroll
        for (int r = 0; r < 4; ++r) {
            const int row = m0 + wr + mi * 16 + lg * 4 + r;
#pragma unroll
            for (int ni = 0; ni < NI; ++ni) {
                const int col = n0 + wc + ni * 16 + l15;
                float v = acc[mi][ni][r] + bias[(MODE == 3) ? row : col];
                if (MODE == 2) v = v * 0.5f * (1.0f + erff(v * 0.70710678118654752f));
                if (MODE == 3)
                    Cb[((size_t)(col >> 10) * 768 + row) * 1024 + (col & 1023)] = (bf16)v;
                else
                    Cb[(size_t)row * ldc + col] = (bf16)v;
            }
        }
    }
}

// ---------------- flash attention (round-11 proven schedule) ----------------
// qk: [8192][1536] bf16 (Q|K per head); vT: [96][64][1024]; grid (8 qb, 96 bh).
// K LDS rows permuted by phys(i)=bits [i5][i3][i2][i4][i1][i0] so the QK^T
// per-lane k-set equals the PV B-fragment layout; P stays in registers.
// Counted-vmcnt barriers (T4); T5 setprio on MFMA clusters; pb/mask inline
// (reg-prefetch refused by regalloc, doubles FETCH — r8/r9). Softmax max uses
// a v_max3 tree (T17) and the denominator a depth-4 pairwise add tree.
__global__ __launch_bounds__(256, 3) void attn_kernel(const bf16* __restrict__ qk,
                                                      const bf16* __restrict__ pbs,
                                                      const bf16* __restrict__ maskb,
                                                      const bf16* __restrict__ vT,
                                                      bf16* __restrict__ ctx) {
    __shared__ __align__(16) bf16 Kb[3][64 * 64];
    __shared__ __align__(16) bf16 Vb[3][64 * 64];
    const int tid = threadIdx.x, wid = tid >> 6, lane = tid & 63;
    const int bh = blockIdx.y, b = bh / 12, h = bh % 12;
    const int q0 = blockIdx.x * 128 + wid * 32;
    const int lg = lane >> 4, l15 = lane & 15;
    const float cqk = 0.18033688011112042f;  // 0.125 * log2(e)

    bf16x8 aq[2][2];
#pragma unroll
    for (int qs = 0; qs < 2; ++qs) {
        const size_t r = (size_t)(b * 1024 + q0 + qs * 16 + l15) * 1536 + h * 64 + 8 * lg;
        aq[qs][0] = *(const bf16x8*)(qk + r);
        aq[qs][1] = *(const bf16x8*)(qk + r + 32);
    }

    auto stage = [&](int tt, int pp) {
#pragma unroll
        for (int rd = 0; rd < 2; ++rd) {
            const int n = rd * 256 + tid;
            const int i = n >> 3, sl = n & 7, c = sl ^ (i & 7);
            const int sig = (i & 32) | ((i & 12) << 1) | ((i & 16) >> 2) | (i & 3);
            gload16(qk + (size_t)(b * 1024 + tt * 64 + sig) * 1536 + 768 + h * 64 + c * 8,
                    (char*)Kb[pp] + (rd * 256 + wid * 64) * 16);
            gload16(vT + ((size_t)bh * 64 + i) * 1024 + tt * 64 + c * 8,
                    (char*)Vb[pp] + (rd * 256 + wid * 64) * 16);
        }
    };

    float mrun[2] = {-1e30f, -1e30f}, lsum[2] = {0.f, 0.f};
    f32x4 acc[2][4] = {};

    stage(0, 0);
    stage(1, 1);
    asm volatile("s_waitcnt vmcnt(4)" ::: "memory");
    __builtin_amdgcn_s_barrier();
    for (int t = 0; t < 16; ++t) {
        const int p = t % 3;
        const int k0 = t * 64;
        bf16x8 pbv[2][2], mkv[2][2];
#pragma unroll
        for (int qs = 0; qs < 2; ++qs) {
            const int q = q0 + qs * 16 + l15;
            const bf16* pr = pbs + ((size_t)h * 1024 + q) * 1024 + k0 + lg * 8;
            const bf16* mr = maskb + ((size_t)b * 1024 + q) * 1024 + k0 + lg * 8;
            pbv[qs][0] = *(const bf16x8*)pr;  pbv[qs][1] = *(const bf16x8*)(pr + 32);
            mkv[qs][0] = *(const bf16x8*)mr;  mkv[qs][1] = *(const bf16x8*)(mr + 32);
        }
        if (t < 14) stage(t + 2, (t + 2) % 3);

        bf16x8 bk[4][2];
#pragma unroll
        for (int kt = 0; kt < 4; ++kt) {
            const int row = kt * 16 + l15;
            const int byte = (row * 128 + lg * 16) ^ ((row & 7) << 4);
            bk[kt][0] = *(const bf16x8*)((const char*)Kb[p] + byte);
            bk[kt][1] = *(const bf16x8*)((const char*)Kb[p] + (byte ^ 64));
        }
        f32x4 s[2][4];
        __builtin_amdgcn_s_setprio(1);
#pragma unroll
        for (int qs = 0; qs < 2; ++qs)
#pragma unroll
            for (int kt = 0; kt < 4; ++kt) {
                f32x4 z = {};
                z = __builtin_amdgcn_mfma_f32_16x16x32_bf16(bk[kt][0], aq[qs][0], z, 0, 0, 0);
                z = __builtin_amdgcn_mfma_f32_16x16x32_bf16(bk[kt][1], aq[qs][1], z, 0, 0, 0);
                s[qs][kt] = z;
            }
        __builtin_amdgcn_s_setprio(0);
#pragma unroll
        for (int qs = 0; qs < 2; ++qs)
#pragma unroll
            for (int kt = 0; kt < 4; ++kt)
#pragma unroll
                for (int r = 0; r < 4; ++r) {
                    const int j = (kt & 1) * 4 + r;
                    s[qs][kt][r] = s[qs][kt][r] * cqk
                                 + (float)pbv[qs][kt >> 1][j]
                                 + (float)mkv[qs][kt >> 1][j];
                }
        // online softmax with defer-max (T13): skip rescale while growth <= 6
        bf16x8 po[2][2];
#pragma unroll
        for (int qs = 0; qs < 2; ++qs) {
            // v_max3 tree (8 ops, depth 3) instead of 15-op serial chain
            float t0 = fmaxf(fmaxf(s[qs][0][0], s[qs][0][1]), s[qs][0][2]);
            float t1 = fmaxf(fmaxf(s[qs][0][3], s[qs][1][0]), s[qs][1][1]);
            float t2 = fmaxf(fmaxf(s[qs][1][2], s[qs][1][3]), s[qs][2][0]);
            float t3 = fmaxf(fmaxf(s[qs][2][1], s[qs][2][2]), s[qs][2][3]);
            float t4 = fmaxf(fmaxf(s[qs][3][0], s[qs][3][1]), s[qs][3][2]);
            float u0 = fmaxf(fmaxf(t0, t1), t2);
            float tm = fmaxf(fmaxf(fmaxf(t3, t4), s[qs][3][3]), u0);
            tm = fmaxf(tm, __shfl_xor(tm, 16));
            tm = fmaxf(tm, __shfl_xor(tm, 32));
            if (!__all(tm <= mrun[qs] + 6.0f)) {
                const float mn = fmaxf(mrun[qs], tm);
                const float scal = __builtin_amdgcn_exp2f(mrun[qs] - mn);
                mrun[qs] = mn;
                lsum[qs] *= scal;
#pragma unroll
                for (int dt = 0; dt < 4; ++dt) {
                    acc[qs][dt][0] *= scal; acc[qs][dt][1] *= scal;
                    acc[qs][dt][2] *= scal; acc[qs][dt][3] *= scal;
                }
            }
            float pvv[16];
#pragma unroll
            for (int kt = 0; kt < 4; ++kt)
#pragma unroll
                for (int r = 0; r < 4; ++r) {
                    const float pv = __builtin_amdgcn_exp2f(s[qs][kt][r] - mrun[qs]);
                    const int idx = kt * 4 + r;
                    pvv[idx] = pv;
                    if (idx < 8) po[qs][0][idx] = (bf16)pv;
                    else         po[qs][1][idx - 8] = (bf16)pv;
                }
            // depth-4 pairwise add tree (shorter dependence chain than serial)
            float a0 = pvv[0] + pvv[1],  a1 = pvv[2] + pvv[3];
            float a2 = pvv[4] + pvv[5],  a3 = pvv[6] + pvv[7];
            float a4 = pvv[8] + pvv[9],  a5 = pvv[10] + pvv[11];
            float a6 = pvv[12] + pvv[13], a7 = pvv[14] + pvv[15];
            float b0 = a0 + a1, b1 = a2 + a3, b2 = a4 + a5, b3 = a6 + a7;
            float ts = (b0 + b1) + (b2 + b3);
            ts += __shfl_xor(ts, 16);
            ts += __shfl_xor(ts, 32);
            lsum[qs] += ts;
        }
        bf16x8 vb[4][2];
#pragma unroll
        for (int dt = 0; dt < 4; ++dt) {
            const int row = dt * 16 + l15;
            const int byte = (row * 128 + lg * 16) ^ ((row & 7) << 4);
            vb[dt][0] = *(const bf16x8*)((const char*)Vb[p] + byte);
            vb[dt][1] = *(const bf16x8*)((const char*)Vb[p] + (byte ^ 64));
        }
        __builtin_amdgcn_s_setprio(1);
#pragma unroll
        for (int qs = 0; qs < 2; ++qs)
#pragma unroll
            for (int dt = 0; dt < 4; ++dt) {
                acc[qs][dt] = __builtin_amdgcn_mfma_f32_16x16x32_bf16(vb[dt][0], po[qs][0], acc[qs][dt], 0, 0, 0);
                acc[qs][dt] = __builtin_amdgcn_mfma_f32_16x16x32_bf16(vb[dt][1], po[qs][1], acc[qs][dt], 0, 0, 0);
            }
        __builtin_amdgcn_s_setprio(0);
        asm volatile("s_waitcnt vmcnt(4)" ::: "memory");
        __builtin_amdgcn_s_barrier();
    }
    // epilogue: O^T[d][q] -> per-wave LDS transpose (reuse Kb) -> coalesced stores
    char* scr = (char*)Kb + wid * 4096;
#pragma unroll
    for (int qs = 0; qs < 2; ++qs) {
        const float inv = 1.0f / lsum[qs];
        const int ql = qs * 16 + l15;
#pragma unroll
        for (int dt = 0; dt < 4; ++dt) {
            bf16x4 o;
#pragma unroll
            for (int r = 0; r < 4; ++r) o[r] = (bf16)(acc[qs][dt][r] * inv);
            const int wb = (ql * 128 + dt * 32 + lg * 8) ^ ((ql & 7) << 4);
            *(bf16x4*)(scr + wb) = o;
        }
    }
    __syncthreads();
#pragma unroll
    for (int qs = 0; qs < 2; ++qs) {
        const int ql = qs * 16 + l15;
        const int rb = (ql * 128 + lg * 32) ^ ((ql & 7) << 4);
        bf16x8 o0 = *(const bf16x8*)(scr + rb);
        bf16x8 o1 = *(const bf16x8*)(scr + (rb ^ 16));
        bf16* cp = ctx + (size_t)(b * 1024 + q0 + ql) * 768 + h * 64 + lg * 16;
        *(bf16x8*)cp = o0;
        *(bf16x8*)(cp + 8) = o1;
    }
}

// ---------------- layernorm ----------------
// MODE 0 (LN1): x bf16 + res f32 -> out bf16.
// MODE 1 (LN2): x bf16 + res bf16 -> out f32.
template<int MODE>
__global__ __launch_bounds__(256) void ln_kernel(const bf16* __restrict__ xb,
                                                 const float* __restrict__ resf,
                                                 const bf16* __restrict__ resb,
                                                 const float* __restrict__ g, const float* __restrict__ bt,
                                                 float* __restrict__ outf, bf16* __restrict__ outb) {
    const int wid = threadIdx.x >> 6, lane = threadIdx.x & 63;
    const int row = blockIdx.x * 4 + wid;
    float4 v[3];
    float s = 0.f, ss = 0.f;
#pragma unroll
    for (int j = 0; j < 3; ++j) {
        bf16x4 xa = ((const bf16x4*)(xb + (size_t)row * 768))[lane + 64 * j];
        float4 b;
        if (MODE == 0) {
            b = ((const float4*)(resf + (size_t)row * 768))[lane + 64 * j];
        } else {
            bf16x4 rb = ((const bf16x4*)(resb + (size_t)row * 768))[lane + 64 * j];
            b.x = (float)rb[0]; b.y = (float)rb[1]; b.z = (float)rb[2]; b.w = (float)rb[3];
        }
        float4 w;
        w.x = (float)xa[0] + b.x; w.y = (float)xa[1] + b.y;
        w.z = (float)xa[2] + b.z; w.w = (float)xa[3] + b.w;
        v[j] = w;
        s += w.x + w.y + w.z + w.w;
        ss += w.x * w.x + w.y * w.y + w.z * w.z + w.w * w.w;
    }
#pragma unroll
    for (int off = 1; off <= 32; off <<= 1) { s += __shfl_xor(s, off); ss += __shfl_xor(ss, off); }
    const float mean = s * (1.f / 768.f);
    float var = (ss - 768.f * mean * mean) * (1.f / 767.f);
    var = fmaxf(var, 0.f);
    const float inv = 1.f / (sqrtf(var) + 1e-6f);
#pragma unroll
    for (int j = 0; j < 3; ++j) {
        float4 gv = ((const float4*)g)[lane + 64 * j];
        float4 bv = ((const float4*)bt)[lane + 64 * j];
        float4 y;
        y.x = gv.x * (v[j].x - mean) * inv + bv.x;
        y.y = gv.y * (v[j].y - mean) * inv + bv.y;
        y.z = gv.z * (v[j].z - mean) * inv + bv.z;
        y.w = gv.w * (v[j].w - mean) * inv + bv.w;
        if (MODE == 1) {
            ((float4*)(outf + (size_t)row * 768))[lane + 64 * j] = y;
        } else {
            bf16x4 o;
            o[0] = (bf16)y.x; o[1] = (bf16)y.y; o[2] = (bf16)y.z; o[3] = (bf16)y.w;
            ((bf16x4*)(outb + (size_t)row * 768))[lane + 64 * j] = o;
        }
    }
}

// ---------------- launcher ----------------

extern "C" void kernel_launch(void* const* d_in, const int* in_sizes, int n_in,
                              void* d_out, int out_size, void* d_ws, size_t ws_size,
                              hipStream_t stream) {
    const float* hidden = (const float*)d_in[0];
    const float* mask   = (const float*)d_in[1];
    const float* pb     = (const float*)d_in[2];
    const float* Wq = (const float*)d_in[3];
    const float* bq = (const float*)d_in[4];
    const float* Wk = (const float*)d_in[5];
    const float* bk = (const float*)d_in[6];
    const float* Wv = (const float*)d_in[7];
    const float* bv = (const float*)d_in[8];
    const float* Wo = (const float*)d_in[9];
    const float* bo = (const float*)d_in[10];
    const float* W1 = (const float*)d_in[11];
    const float* b1 = (const float*)d_in[12];
    const float* W2 = (const float*)d_in[13];
    const float* b2 = (const float*)d_in[14];
    const float* g1  = (const float*)d_in[15];
    const float* be1 = (const float*)d_in[16];
    const float* g2  = (const float*)d_in[17];
    const float* be2 = (const float*)d_in[18];
    float* out = (float*)d_out;

    char* ws = (char*)d_ws;
    bf16*  xbf      = (bf16*)(ws);                       // 12,582,912 ; later inter_bf
    bf16*  wqkv_t   = (bf16*)(ws + 12582912);            // 3,538,944  [wq_t|wk_t|wv_t]
    bf16*  wo_t     = (bf16*)(ws + 16121856);            // 1,179,648
    bf16*  w1_t     = (bf16*)(ws + 17301504);            // 4,718,592
    bf16*  w2_t     = (bf16*)(ws + 22020096);            // 4,718,592
    float* bqk      = (float*)(ws + 26738688);           // 9,216
    bf16*  qk       = (bf16*)(ws + 26747904);            // 25,165,824 [8192][1536]
    bf16*  ffn1     = qk;                                // 50,331,648 span (qk+vT dead)
    bf16*  vT       = (bf16*)(ws + 26747904 + 25165824); // 12,582,912
    bf16*  ctx      = (bf16*)(ws + 77079552);            // 12,582,912
    bf16*  pbs      = (bf16*)(ws + 89662464);            // 25,165,824 (dead after attn)
    bf16*  attn_outb= (bf16*)(ws + 89662464);            // 12,582,912 (reuses pbs)
    bf16*  maskb    = (bf16*)(ws + 114828288);           // 16,777,216 (dead after attn)
    bf16*  ffn2b    = (bf16*)(ws + 114828288);           // 12,582,912 (reuses maskb)
    bf16*  interb   = xbf;
    bf16*  wv_t     = wqkv_t + 2 * 768 * 768;

    prep_all_kernel<<<33838, 256, 0, stream>>>(hidden, xbf,
                                               Wq, Wk, Wv, Wo,
                                               wqkv_t, wqkv_t + 768 * 768, wv_t, wo_t,
                                               W1, w1_t, W2, w2_t,
                                               pb, mask, bq, bk, pbs, maskb, bqk);

    gemm_kernel<0, 128><<<dim3(12, 64), 256, 0, stream>>>(xbf, wqkv_t, bqk, qk, 8192, 1536, 768, 1536);
    gemm_kernel<3, 128><<<dim3(64, 6), 256, 0, stream>>>(wv_t, xbf, bv, vT, 768, 8192, 768, 0);
    attn_kernel<<<dim3(8, 96), 256, 0, stream>>>(qk, pbs, maskb, vT, ctx);
    gemm_kernel<0, 64><<<dim3(12, 64), 256, 0, stream>>>(ctx, wo_t, bo, attn_outb, 8192, 768, 768, 768);
    ln_kernel<0><<<2048, 256, 0, stream>>>(attn_outb, hidden, nullptr, g1, be1, nullptr, interb);
    gemm_kernel<2, 128><<<dim3(24, 64), 256, 0, stream>>>(interb, w1_t, b1, ffn1, 8192, 3072, 768, 3072);
    gemm_kernel<0, 64><<<dim3(12, 64), 256, 0, stream>>>(ffn1, w2_t, b2, ffn2b, 8192, 768, 3072, 768);
    ln_kernel<1><<<2048, 256, 0, stream>>>(ffn2b, nullptr, interb, g2, be2, out, nullptr);
}